// Round 8
// baseline (23.185 us; speedup 1.0000x reference)
//
#include <hip/hip_runtime.h>

#define DD 256        // feature dim
#define CC 4096       // number of centers
#define NB 128        // blocks (one barrier group; 128 CUs in phase 1)
#define TPB 512       // threads/block = 8 waves
#define RPB (CC / NB) // 32 rows per block (4 per wave)
#define D4 (DD / 4)   // 64 float4 columns per row
#define MAGIC 0x05F3A9C1  // != 0 (self-reset) and != 0xAAAAAAAA (ws poison)

// ---------------------------------------------------------------------------
// DensityLoss forward, collapsed O(C^2 D) -> O(C D), ONE graph node:
//   t[d]  = sum_i centers[i][d];  S = sum_i ||c_i||^2
//   cd[i] = (C*||c_i||^2 + S - 2*c_i.t) / (C-1)      (diagonal term == 0)
//   out   = (sum cd / C) / var(cd, ddof=1) / N
// R5's proven protocol, R6's geometry, ISOLATED: packed magic-value flag
// arrays (one line fetch observes 16 flags; 8 lines total), block 0
// self-resets flags at the end (safe: only after every block set flag2;
// 0xAA poison != MAGIC too). Rows live in registers across the barrier;
// centers is read exactly once. All reductions fixed-order -> deterministic.
// ---------------------------------------------------------------------------
__global__ __launch_bounds__(TPB) void fused_density(
    const float* __restrict__ centers,
    float* __restrict__ t_part,    // [NB][DD]
    float* __restrict__ S_part,    // [NB] packed
    double* __restrict__ cd_part,  // [NB] packed
    double* __restrict__ cd2_part, // [NB] packed
    int* __restrict__ flag1,       // [NB] packed
    int* __restrict__ flag2,       // [NB] packed
    float* __restrict__ out, long long N) {
  const int tx = threadIdx.x, w = tx >> 6, lane = tx & 63, b = blockIdx.x;

  __shared__ float4 smT[8][64];  // wave column partials (8 KB)
  __shared__ float sm2[2][DD];   // half-reduced t partials
  __shared__ float smt[DD];      // final t
  __shared__ float sS[8];
  __shared__ float sSfin;
  __shared__ double sC[8], sC2[8];
  __shared__ double rc[NB], rc2[NB];

  // ---- phase 1: per-block column sums + sum-of-squares (rows -> regs) ----
  const float4* src =
      (const float4*)centers + (size_t)(b * RPB + w * 4) * D4 + lane;
  float4 v0 = src[0 * D4], v1 = src[1 * D4], v2 = src[2 * D4], v3 = src[3 * D4];

  float4 ta;
  ta.x = (v0.x + v1.x) + (v2.x + v3.x);
  ta.y = (v0.y + v1.y) + (v2.y + v3.y);
  ta.z = (v0.z + v1.z) + (v2.z + v3.z);
  ta.w = (v0.w + v1.w) + (v2.w + v3.w);
  smT[w][lane] = ta;
  float ss = (v0.x * v0.x + v0.y * v0.y + v0.z * v0.z + v0.w * v0.w) +
             (v1.x * v1.x + v1.y * v1.y + v1.z * v1.z + v1.w * v1.w) +
             (v2.x * v2.x + v2.y * v2.y + v2.z * v2.z + v2.w * v2.w) +
             (v3.x * v3.x + v3.y * v3.y + v3.z * v3.z + v3.w * v3.w);
  #pragma unroll
  for (int off = 32; off; off >>= 1) ss += __shfl_xor(ss, off, 64);
  if (lane == 0) sS[w] = ss;
  __syncthreads();
  if (tx < 64) {
    float4 s = smT[0][tx];
    #pragma unroll
    for (int k = 1; k < 8; ++k) {
      float4 o = smT[k][tx];
      s.x += o.x; s.y += o.y; s.z += o.z; s.w += o.w;
    }
    ((float4*)t_part)[b * 64 + tx] = s;
  }
  if (tx == 0) {
    float s = 0.f;
    #pragma unroll
    for (int k = 0; k < 8; ++k) s += sS[k];
    S_part[b] = s;
  }
  __syncthreads();  // block's t_part/S_part stores complete before release
  if (tx == 0)
    __hip_atomic_store(&flag1[b], MAGIC, __ATOMIC_RELEASE,
                       __HIP_MEMORY_SCOPE_AGENT);

  // ---- grid barrier: every block waits for all NB flag1 (packed spin) ----
  if (tx < NB) {
    while (__hip_atomic_load(&flag1[tx], __ATOMIC_ACQUIRE,
                             __HIP_MEMORY_SCOPE_AGENT) != MAGIC)
      __builtin_amdgcn_s_sleep(1);
  }
  __syncthreads();

  // ---- phase 2: t finalize (512 thr, 2/column, 8-way ILP over 64 each) ----
  {
    const int col = tx & 255, half = tx >> 8;
    const float* tp = t_part + (size_t)(half * 64) * DD + col;
    float a0 = 0.f, a1 = 0.f, a2 = 0.f, a3 = 0.f;
    float a4 = 0.f, a5 = 0.f, a6 = 0.f, a7 = 0.f;
    #pragma unroll
    for (int p = 0; p < 64; p += 8) {
      a0 += tp[(p + 0) * DD]; a1 += tp[(p + 1) * DD];
      a2 += tp[(p + 2) * DD]; a3 += tp[(p + 3) * DD];
      a4 += tp[(p + 4) * DD]; a5 += tp[(p + 5) * DD];
      a6 += tp[(p + 6) * DD]; a7 += tp[(p + 7) * DD];
    }
    sm2[half][col] = ((a0 + a1) + (a2 + a3)) + ((a4 + a5) + (a6 + a7));
  }
  __syncthreads();
  if (tx < DD) {
    smt[tx] = sm2[0][tx] + sm2[1][tx];
  } else if (tx >= 256 && tx < 320) {  // wave 4: S over 128 packed slots
    const int l = tx - 256;
    float sv = S_part[l] + S_part[l + 64];
    #pragma unroll
    for (int off = 32; off; off >>= 1) sv += __shfl_xor(sv, off, 64);
    if (l == 0) sSfin = sv;
  }
  __syncthreads();
  const float S = sSfin;
  const float4 t4 = ((const float4*)smt)[lane];

  // ---- phase 3: cd for this block's rows (still in registers) ----
  const float Cf = (float)CC;
  const double inv = 1.0 / (double)(CC - 1);
  double cds = 0.0, cd2 = 0.0;
  #pragma unroll
  for (int r = 0; r < 4; ++r) {
    float4 v = (r == 0) ? v0 : (r == 1) ? v1 : (r == 2) ? v2 : v3;
    float u = (Cf * v.x - 2.f * t4.x) * v.x + (Cf * v.y - 2.f * t4.y) * v.y +
              (Cf * v.z - 2.f * t4.z) * v.z + (Cf * v.w - 2.f * t4.w) * v.w;
    #pragma unroll
    for (int off = 32; off; off >>= 1) u += __shfl_xor(u, off, 64);
    if (lane == 0) {
      double cd = ((double)u + (double)S) * inv;
      cds += cd;
      cd2 += cd * cd;
    }
  }
  if (lane == 0) { sC[w] = cds; sC2[w] = cd2; }
  __syncthreads();
  if (tx == 0) {
    double bc = 0.0, bc2 = 0.0;
    #pragma unroll
    for (int k = 0; k < 8; ++k) { bc += sC[k]; bc2 += sC2[k]; }
    __hip_atomic_store(&cd_part[b], bc, __ATOMIC_RELEASE,
                       __HIP_MEMORY_SCOPE_AGENT);
    __hip_atomic_store(&cd2_part[b], bc2, __ATOMIC_RELEASE,
                       __HIP_MEMORY_SCOPE_AGENT);
    __hip_atomic_store(&flag2[b], MAGIC, __ATOMIC_RELEASE,
                       __HIP_MEMORY_SCOPE_AGENT);
  }

  // ---- phase 4: block 0 gathers, combines (fixed order), resets flags ----
  if (b == 0) {
    if (tx < NB) {
      while (__hip_atomic_load(&flag2[tx], __ATOMIC_ACQUIRE,
                               __HIP_MEMORY_SCOPE_AGENT) != MAGIC)
        __builtin_amdgcn_s_sleep(1);
      rc[tx] = cd_part[tx];
      rc2[tx] = cd2_part[tx];
    }
    __syncthreads();
    #pragma unroll
    for (int st = 64; st; st >>= 1) {
      if (tx < st) { rc[tx] += rc[tx + st]; rc2[tx] += rc2[tx + st]; }
      __syncthreads();
    }
    if (tx == 0) {
      double s = rc[0], s2 = rc2[0];
      double mean = s / (double)CC;
      double var = (s2 - s * s / (double)CC) / (double)(CC - 1);
      out[0] = (float)(mean / var / (double)N);
    }
    // every block has set flag2 => every block passed every spin => safe
    if (tx < NB) {
      __hip_atomic_store(&flag1[tx], 0, __ATOMIC_RELEASE,
                         __HIP_MEMORY_SCOPE_AGENT);
      __hip_atomic_store(&flag2[tx], 0, __ATOMIC_RELEASE,
                         __HIP_MEMORY_SCOPE_AGENT);
    }
  }
}

extern "C" void kernel_launch(void* const* d_in, const int* in_sizes, int n_in,
                              void* d_out, int out_size, void* d_ws,
                              size_t ws_size, hipStream_t stream) {
  const float* centers = (const float*)d_in[0];
  long long N = (long long)in_sizes[2];  // labels.shape[0]
  (void)n_in; (void)out_size; (void)ws_size;

  // ws: t_part 128KB | S_part 512B | cd 1KB | cd2 1KB | flag1 512B | flag2
  char* ws = (char*)d_ws;
  float* t_part = (float*)ws;                    // 131072 B
  float* S_part = (float*)(ws + 131072);         // 512 B
  double* cd_part = (double*)(ws + 131584);      // 1024 B (8B aligned)
  double* cd2_part = (double*)(ws + 132608);     // 1024 B
  int* flag1 = (int*)(ws + 133632);              // 512 B
  int* flag2 = (int*)(ws + 134144);              // 512 B
  float* outp = (float*)d_out;

  hipLaunchKernelGGL(fused_density, dim3(NB), dim3(TPB), 0, stream, centers,
                     t_part, S_part, cd_part, cd2_part, flag1, flag2, outp, N);
}

// Round 9
// 17.052 us; speedup vs baseline: 1.3596x; 1.3596x over previous
//
#include <hip/hip_runtime.h>

#define DD 256        // feature dim
#define CC 4096       // number of centers
#define NB 64         // blocks (one barrier group)
#define TPB 1024      // threads/block = 16 waves
#define RPB (CC / NB) // 64 rows per block (4 per wave)
#define D4 (DD / 4)   // 64 float4 columns per row
#define MAGIC 0x05F3A9C1  // != 0 (self-reset) and != 0xAAAAAAAA (ws poison)

// ---------------------------------------------------------------------------
// DensityLoss forward, collapsed O(C^2 D) -> O(C D), ONE graph node.
// BEST MEASURED CONFIG (R5: 16.9 us). NB=64 is the sweet spot: phase-2
// redundant traffic scales as NB^2 (R8: NB=128 packed -> 23.2 us), node
// count costs ~5.6 us each (R4->R5), padded comm lines hurt the packed
// spin (R6). Do not change geometry without an isolated A/B.
//   t[d]  = sum_i centers[i][d];  S = sum_i ||c_i||^2
//   cd[i] = (C*||c_i||^2 + S - 2*c_i.t) / (C-1)      (diagonal term == 0)
//   out   = (sum cd / C) / var(cd, ddof=1) / N
// Magic-value flag protocol: block b release-stores flag=MAGIC after
// publishing; consumers acquire-spin; block 0 resets all flags to 0 at the
// end (safe: only after every block set flag2, i.e. passed every spin; the
// 0xAA ws poison != MAGIC too). Rows live in registers across the barrier;
// centers is read exactly once. All reductions fixed-order -> deterministic.
// ---------------------------------------------------------------------------
__global__ __launch_bounds__(TPB) void fused_density(
    const float* __restrict__ centers,
    float* __restrict__ t_part,    // [NB][DD]
    float* __restrict__ S_part,    // [NB]
    double* __restrict__ cd_part,  // [NB]
    double* __restrict__ cd2_part, // [NB]
    int* __restrict__ flag1,       // [NB] packed
    int* __restrict__ flag2,       // [NB] packed
    float* __restrict__ out, long long N) {
  const int tx = threadIdx.x, w = tx >> 6, lane = tx & 63, b = blockIdx.x;

  __shared__ float4 smT[16][64];  // wave column partials (16 KB)
  __shared__ float sm2[2][DD];    // half-reduced t partials
  __shared__ float smt[DD];       // final t
  __shared__ float sSfin;
  __shared__ float sS[16];
  __shared__ double sC[16], sC2[16];
  __shared__ double rc[64], rc2[64];

  // ---- phase 1: per-block column sums + sum-of-squares (rows -> regs) ----
  const float4* src =
      (const float4*)centers + (size_t)(b * RPB + w * 4) * D4 + lane;
  float4 v0 = src[0 * D4], v1 = src[1 * D4], v2 = src[2 * D4], v3 = src[3 * D4];

  float4 ta;
  ta.x = (v0.x + v1.x) + (v2.x + v3.x);
  ta.y = (v0.y + v1.y) + (v2.y + v3.y);
  ta.z = (v0.z + v1.z) + (v2.z + v3.z);
  ta.w = (v0.w + v1.w) + (v2.w + v3.w);
  smT[w][lane] = ta;
  float ss = (v0.x * v0.x + v0.y * v0.y + v0.z * v0.z + v0.w * v0.w) +
             (v1.x * v1.x + v1.y * v1.y + v1.z * v1.z + v1.w * v1.w) +
             (v2.x * v2.x + v2.y * v2.y + v2.z * v2.z + v2.w * v2.w) +
             (v3.x * v3.x + v3.y * v3.y + v3.z * v3.z + v3.w * v3.w);
  #pragma unroll
  for (int off = 32; off; off >>= 1) ss += __shfl_xor(ss, off, 64);
  if (lane == 0) sS[w] = ss;
  __syncthreads();
  if (tx < 64) {
    float4 s = smT[0][tx];
    #pragma unroll
    for (int k = 1; k < 16; ++k) {
      float4 o = smT[k][tx];
      s.x += o.x; s.y += o.y; s.z += o.z; s.w += o.w;
    }
    ((float4*)t_part)[b * 64 + tx] = s;
  }
  if (tx == 0) {
    float s = 0.f;
    #pragma unroll
    for (int k = 0; k < 16; ++k) s += sS[k];
    S_part[b] = s;
  }
  __syncthreads();  // block's t_part/S_part stores complete before release
  if (tx == 0)
    __hip_atomic_store(&flag1[b], MAGIC, __ATOMIC_RELEASE,
                       __HIP_MEMORY_SCOPE_AGENT);

  // ---- grid barrier: every block waits for all 64 flag1 (packed spin) ----
  if (tx < NB) {
    while (__hip_atomic_load(&flag1[tx], __ATOMIC_ACQUIRE,
                             __HIP_MEMORY_SCOPE_AGENT) != MAGIC)
      __builtin_amdgcn_s_sleep(1);
  }
  __syncthreads();

  // ---- phase 2: redundant t finalize (512 thr, 8-way ILP) + S butterfly ---
  if (tx < 512) {
    const int col = tx & 255, half = tx >> 8;
    const float* tp = t_part + (size_t)half * 32 * DD + col;
    float a0 = 0.f, a1 = 0.f, a2 = 0.f, a3 = 0.f;
    float a4 = 0.f, a5 = 0.f, a6 = 0.f, a7 = 0.f;
    #pragma unroll
    for (int p = 0; p < 32; p += 8) {
      a0 += tp[(p + 0) * DD]; a1 += tp[(p + 1) * DD];
      a2 += tp[(p + 2) * DD]; a3 += tp[(p + 3) * DD];
      a4 += tp[(p + 4) * DD]; a5 += tp[(p + 5) * DD];
      a6 += tp[(p + 6) * DD]; a7 += tp[(p + 7) * DD];
    }
    sm2[half][col] = ((a0 + a1) + (a2 + a3)) + ((a4 + a5) + (a6 + a7));
  } else if (tx >= 512 && tx < 576) {  // wave 8: S via one 64-lane butterfly
    float sv = S_part[tx - 512];
    #pragma unroll
    for (int off = 32; off; off >>= 1) sv += __shfl_xor(sv, off, 64);
    if (tx == 512) sSfin = sv;
  }
  __syncthreads();
  if (tx < DD) smt[tx] = sm2[0][tx] + sm2[1][tx];
  __syncthreads();
  const float S = sSfin;
  const float4 t4 = ((const float4*)smt)[lane];

  // ---- phase 3: cd for this block's rows (still in registers) ----
  const float Cf = (float)CC;
  const double inv = 1.0 / (double)(CC - 1);
  double cds = 0.0, cd2 = 0.0;
  #pragma unroll
  for (int r = 0; r < 4; ++r) {
    float4 v = (r == 0) ? v0 : (r == 1) ? v1 : (r == 2) ? v2 : v3;
    float u = (Cf * v.x - 2.f * t4.x) * v.x + (Cf * v.y - 2.f * t4.y) * v.y +
              (Cf * v.z - 2.f * t4.z) * v.z + (Cf * v.w - 2.f * t4.w) * v.w;
    #pragma unroll
    for (int off = 32; off; off >>= 1) u += __shfl_xor(u, off, 64);
    if (lane == 0) {
      double cd = ((double)u + (double)S) * inv;
      cds += cd;
      cd2 += cd * cd;
    }
  }
  if (lane == 0) { sC[w] = cds; sC2[w] = cd2; }
  __syncthreads();
  if (tx == 0) {
    double bc = 0.0, bc2 = 0.0;
    #pragma unroll
    for (int k = 0; k < 16; ++k) { bc += sC[k]; bc2 += sC2[k]; }
    __hip_atomic_store(&cd_part[b], bc, __ATOMIC_RELEASE,
                       __HIP_MEMORY_SCOPE_AGENT);
    __hip_atomic_store(&cd2_part[b], bc2, __ATOMIC_RELEASE,
                       __HIP_MEMORY_SCOPE_AGENT);
    __hip_atomic_store(&flag2[b], MAGIC, __ATOMIC_RELEASE,
                       __HIP_MEMORY_SCOPE_AGENT);
  }

  // ---- phase 4: block 0 gathers, combines (fixed order), resets flags ----
  if (b == 0) {
    if (tx < NB) {
      while (__hip_atomic_load(&flag2[tx], __ATOMIC_ACQUIRE,
                               __HIP_MEMORY_SCOPE_AGENT) != MAGIC)
        __builtin_amdgcn_s_sleep(1);
      rc[tx] = cd_part[tx];
      rc2[tx] = cd2_part[tx];
    }
    __syncthreads();
    #pragma unroll
    for (int st = 32; st; st >>= 1) {
      if (tx < st) { rc[tx] += rc[tx + st]; rc2[tx] += rc2[tx + st]; }
      __syncthreads();
    }
    if (tx == 0) {
      double s = rc[0], s2 = rc2[0];
      double mean = s / (double)CC;
      double var = (s2 - s * s / (double)CC) / (double)(CC - 1);
      out[0] = (float)(mean / var / (double)N);
    }
    // every block has set flag2 => every block passed every spin => safe
    if (tx < NB) {
      __hip_atomic_store(&flag1[tx], 0, __ATOMIC_RELEASE,
                         __HIP_MEMORY_SCOPE_AGENT);
      __hip_atomic_store(&flag2[tx], 0, __ATOMIC_RELEASE,
                         __HIP_MEMORY_SCOPE_AGENT);
    }
  }
}

extern "C" void kernel_launch(void* const* d_in, const int* in_sizes, int n_in,
                              void* d_out, int out_size, void* d_ws,
                              size_t ws_size, hipStream_t stream) {
  const float* centers = (const float*)d_in[0];
  long long N = (long long)in_sizes[2];  // labels.shape[0]
  (void)n_in; (void)out_size; (void)ws_size;

  // ws layout: t_part 64KB | S_part 256B | pad | cd 512B | cd2 512B | flags
  char* ws = (char*)d_ws;
  float* t_part = (float*)ws;                    // 65536 B
  float* S_part = (float*)(ws + 65536);          // 256 B
  double* cd_part = (double*)(ws + 66048);       // 512 B (8B aligned)
  double* cd2_part = (double*)(ws + 66560);      // 512 B
  int* flag1 = (int*)(ws + 67072);               // 256 B
  int* flag2 = (int*)(ws + 67328);               // 256 B
  float* outp = (float*)d_out;

  hipLaunchKernelGGL(fused_density, dim3(NB), dim3(TPB), 0, stream, centers,
                     t_part, S_part, cd_part, cd2_part, flag1, flag2, outp, N);
}